// Round 11
// baseline (273.653 us; speedup 1.0000x reference)
//
#include <hip/hip_runtime.h>
#include <hip/hip_bf16.h>

typedef __attribute__((ext_vector_type(8))) short bf16x8;
typedef __attribute__((ext_vector_type(4))) float f32x4;
typedef long long i64;

static __device__ __forceinline__ float bflo(unsigned v){ return __uint_as_float(v << 16); }
static __device__ __forceinline__ float bfhi(unsigned v){ return __uint_as_float(v & 0xffff0000u); }
static __device__ __forceinline__ unsigned short f2bf(float f){
  unsigned u = __float_as_uint(f);
  u += 0x7FFFu + ((u >> 16) & 1u);
  return (unsigned short)(u >> 16);
}
// OCP e4m3fn encode, RNE, saturating
static __device__ __forceinline__ unsigned f2e4m3(float x){
  unsigned b = __float_as_uint(x);
  unsigned s = (b >> 31) << 7;
  b &= 0x7fffffffu;
  if (b >= 0x43e80000u) return s | 0x7eu;
  if (b < 0x3c800000u)
    return s | (unsigned)rintf(__uint_as_float(b) * 512.f);
  unsigned b2 = b + 0x7ffffu + ((b >> 20) & 1u);
  return s | (((b2 >> 23) - 120u) << 3) | ((b2 >> 20) & 7u);
}
static __device__ __forceinline__ void gload_lds16(const void* g, void* l){
  __builtin_amdgcn_global_load_lds((const __attribute__((address_space(1))) unsigned int*)g,
                                   (__attribute__((address_space(3))) unsigned int*)l, 16, 0, 0);
}

#define MFMA16(acc, a, b) (acc) = __builtin_amdgcn_mfma_f32_16x16x32_bf16((a),(b),(acc),0,0,0)
#define MFMA8(acc, a, b)  (acc) = __builtin_amdgcn_mfma_f32_16x16x32_fp8_fp8((a),(b),(acc),0,0,0)

#define NB    8
#define NVRT  2562
#define MP    2624     /* rows padded to 82*32 = 164*16 */
#define NRB2  82
#define NRB16 164      /* 16-row blocks (adj) */
#define NKT8  21       /* K tiles of 128 over 2688 */
#define KOCT  336
#define YO    ((size_t)KOCT*128*8)   /* y1p8 per-batch bytes */

// pixel-projection buffer bases (elements), layout [B*HW][128] bf16 per map
#define G_B0 0ul
#define G_B1 3211264ul
#define G_B2 4014080ul
#define G_B3 4214784ul
#define G_TOT 4264960ul

// ---------------------------------------------------------------- unified weight pack: 7 weights -> [Kp/8][128][8] bf16
struct PWArgs {
  const float* src[7];
  unsigned short* dst[7];
  int ksrc[7], nsrc[7];
};
__global__ void k_packw_all(PWArgs a)
{
  const int cb[8] = {0,491520,528384,565248,585728,606208,626688,647168};
  int g = blockIdx.x * 256 + threadIdx.x;
#pragma unroll
  for (int s = 0; s < 7; s++){
    if (g >= cb[s] && g < cb[s+1]){
      int li = g - cb[s];
      int k = li >> 7, c = li & 127;
      int ks = a.ksrc[s], ns = a.nsrc[s];
      float v = (k < ks) ? a.src[s][(size_t)k * ns + c] : 0.f;
      a.dst[s][((size_t)(k >> 3) * 128 + c) * 8 + (k & 7)] = f2bf(v);
    }
  }
}

// ---------------------------------------------------------------- fused conv-read + pixel projection: G_m = ftT_m @ W_m
__global__ __launch_bounds__(256) void k_gproj2(
    const float* __restrict__ c0m, const float* __restrict__ c1m,
    const float* __restrict__ c2m, const float* __restrict__ c3m,
    const unsigned short* __restrict__ wp,
    unsigned short* __restrict__ G)
{
  __shared__ f32x4 red[3][1024];
  int bx = blockIdx.x;
  int m, b, tile;
  if (bx < 784)      { m = 0; b = bx / 98;  tile = bx - b*98; }
  else if (bx < 984) { int l = bx-784;  m = 1; b = l / 25; tile = l - b*25; }
  else if (bx < 1040){ int l = bx-984;  m = 2; b = l / 7;  tile = l - b*7; }
  else               { int l = bx-1040; m = 3; b = l >> 1; tile = l & 1; }
  int C  = 256 << m;
  int HW = (m==0)?3136:(m==1)?784:(m==2)?196:49;
  const float* src = ((m==0)?c0m:(m==1)?c1m:(m==2)?c2m:c3m) + (size_t)b * C * HW;
  size_t gb = ((m==0)?G_B0:(m==1)?G_B1:(m==2)?G_B2:G_B3) + (size_t)b * HW * 128;
  int ko8 = (m==0)?0:(m==1)?32:(m==2)?96:224;

  int t = threadIdx.x, w = t >> 6, lane = t & 63;
  int l15 = lane & 15, l4 = lane >> 4;
  int hw0 = tile * 32;
  int ar0 = min(hw0 + l15, HW - 1);
  int ar1 = min(hw0 + 16 + l15, HW - 1);

  f32x4 acc[2][8];
#pragma unroll
  for (int i = 0; i < 2; i++)
#pragma unroll
    for (int j = 0; j < 8; j++) acc[i][j] = (f32x4){0,0,0,0};

  int kq = C >> 2;
  int kbeg = w * kq, klim = kbeg + kq;
  for (int kb = kbeg; kb < klim; kb += 32){
    bf16x8 a0, a1;
#pragma unroll
    for (int j = 0; j < 8; j++){
      int cc = kb + l4*8 + j;
      a0[j] = (short)f2bf(src[(size_t)cc * HW + ar0]);
      a1[j] = (short)f2bf(src[(size_t)cc * HW + ar1]);
    }
    size_t bo = ((size_t)(ko8 + (kb>>3) + l4) * 128 + l15) * 8;
#pragma unroll
    for (int cf = 0; cf < 8; cf++){
      bf16x8 bb = *(const bf16x8*)(wp + bo + cf*128);
      MFMA16(acc[0][cf], a0, bb);
      MFMA16(acc[1][cf], a1, bb);
    }
  }

  if (w){
#pragma unroll
    for (int rf = 0; rf < 2; rf++)
#pragma unroll
      for (int cf = 0; cf < 8; cf++)
        red[w-1][(rf*8+cf)*64 + lane] = acc[rf][cf];
  }
  __syncthreads();
  if (!w){
#pragma unroll
    for (int rf = 0; rf < 2; rf++)
#pragma unroll
      for (int cf = 0; cf < 8; cf++){
        int i = (rf*8+cf)*64 + lane;
        f32x4 s = acc[rf][cf] + red[0][i] + red[1][i] + red[2][i];
        int col = cf*16 + l15;
#pragma unroll
        for (int r = 0; r < 4; r++){
          int hw = hw0 + rf*16 + l4*4 + r;
          if (hw < HW) G[gb + (size_t)hw*128 + col] = f2bf(s[r]);
        }
      }
  }
}

// ---------------------------------------------------------------- prep: gather-blend from G + vf base + x1/x2 pads + y1 tail-zero (both buffers)
__global__ void k_prep2(const float* __restrict__ vfeat, const float* __restrict__ pos,
                        const unsigned short* __restrict__ G,
                        const float* __restrict__ bias,
                        unsigned short* __restrict__ vf,
                        unsigned short* __restrict__ x1,
                        unsigned short* __restrict__ x2,
                        unsigned char* __restrict__ y1A,
                        unsigned char* __restrict__ y1B)
{
  int b = blockIdx.y;
  if (blockIdx.x == 0){
    unsigned long long* za = (unsigned long long*)(y1A + (size_t)b*YO + (size_t)328*128*8);
    unsigned long long* zb = (unsigned long long*)(y1B + (size_t)b*YO + (size_t)328*128*8);
    int i = threadIdx.x;
#pragma unroll
    for (int j = 0; j < 4; j++){ za[i*4+j] = 0; zb[i*4+j] = 0; }
  }
  int row = blockIdx.x * 4 + (threadIdx.x >> 6);
  int lane = threadIdx.x & 63;
  size_t vfo = ((size_t)b * MP + row) * 288;
  size_t xo  = ((size_t)b * MP + row) * 160;
  if (row < NVRT){
    size_t src = (size_t)b * NVRT + row;
    float px = fminf(fmaxf(pos[src*3 + 0], -1.f), 1.f);
    float py = fminf(fmaxf(pos[src*3 + 1], -1.f), 1.f);
    int c0 = lane * 2;
    float s0 = bias[c0], s1 = bias[c0 + 1];
#pragma unroll
    for (int m = 0; m < 4; m++){
      int W = 56 >> m;
      int HW = W * W;
      size_t gb = (m==0)?G_B0:(m==1)?G_B1:(m==2)?G_B2:G_B3;
      float gx = (px + 1.f) * 0.5f * (float)(W - 1);
      float gy = (py + 1.f) * 0.5f * (float)(W - 1);
      int x0 = (int)floorf(gx), y0 = (int)floorf(gy);
      float wx = gx - (float)x0, wy = gy - (float)y0;
      int x1i = min(x0 + 1, W - 1), y1i = min(y0 + 1, W - 1);
      const unsigned short* g = G + gb + (size_t)b * HW * 128;
      unsigned v00 = *(const unsigned*)(g + ((size_t)(y0 *W + x0 ))*128 + c0);
      unsigned v01 = *(const unsigned*)(g + ((size_t)(y0 *W + x1i))*128 + c0);
      unsigned v10 = *(const unsigned*)(g + ((size_t)(y1i*W + x0 ))*128 + c0);
      unsigned v11 = *(const unsigned*)(g + ((size_t)(y1i*W + x1i))*128 + c0);
      float w00 = (1.f-wx)*(1.f-wy), w01 = wx*(1.f-wy);
      float w10 = (1.f-wx)*wy,       w11 = wx*wy;
      s0 += w00*bflo(v00) + w01*bflo(v01) + w10*bflo(v10) + w11*bflo(v11);
      s1 += w00*bfhi(v00) + w01*bfhi(v01) + w10*bfhi(v10) + w11*bfhi(v11);
    }
    vf[vfo + 131 + c0]     = f2bf(s0);
    vf[vfo + 131 + c0 + 1] = f2bf(s1);
    float2 fv = *(const float2*)(vfeat + src*128 + c0);
    vf[vfo + c0]     = f2bf(fv.x);
    vf[vfo + c0 + 1] = f2bf(fv.y);
    if (lane < 3){
      unsigned short v = f2bf(pos[src*3 + lane]);
      vf[vfo + 128 + lane] = v;
      x1[xo + lane] = v;
      x2[xo + lane] = v;
    }
    if (lane >= 32 && lane < 61) vf[vfo + 259 + (lane - 32)] = 0;
    if (lane < 29){ x1[xo + 131 + lane] = 0; x2[xo + 131 + lane] = 0; }
  } else {
    for (int c = lane; c < 288; c += 64) vf[vfo + c] = 0;
    for (int c = lane; c < 160; c += 64){ x1[xo + c] = 0; x2[xo + c] = 0; }
  }
}

// ---------------------------------------------------------------- y1p8 = fp8(x @ w1)  (first gc only)
template<int KX>
__global__ __launch_bounds__(256) void k_y1(
    const unsigned short* __restrict__ x,
    const unsigned short* __restrict__ wp1,
    unsigned char* __restrict__ y1p8)
{
  int b = blockIdx.y, rb = blockIdx.x * 32;
  int t = threadIdx.x, wave = t >> 6, lane = t & 63;
  int rf = wave & 1, ch = wave >> 1;
  int l15 = lane & 15, l4 = lane >> 4;
  f32x4 a1[4];
#pragma unroll
  for (int c = 0; c < 4; c++) a1[c] = (f32x4){0,0,0,0};
  int row = rb + rf*16 + l15;
  const unsigned short* xp = x + ((size_t)b * MP + row) * KX + l4 * 8;
#pragma unroll
  for (int kb = 0; kb < KX; kb += 32){
    bf16x8 a = *(const bf16x8*)(xp + kb);
    size_t bo = ((size_t)((kb>>3) + l4) * 128 + ch*64 + l15) * 8;
#pragma unroll
    for (int c = 0; c < 4; c++){
      bf16x8 b1 = *(const bf16x8*)(wp1 + bo + c*128);
      MFMA16(a1[c], a, b1);
    }
  }
  unsigned char* yb = y1p8 + (size_t)b * YO;
#pragma unroll
  for (int c = 0; c < 4; c++){
    int col = ch*64 + c*16 + l15;
    int orow0 = rb + rf*16 + l4*4;
    unsigned q = f2e4m3(a1[c][0]) | (f2e4m3(a1[c][1]) << 8)
               | (f2e4m3(a1[c][2]) << 16) | (f2e4m3(a1[c][3]) << 24);
    *(unsigned*)(yb + ((size_t)(orow0 >> 3) * 128 + col) * 8 + (orow0 & 7)) = q;
  }
}

// ---------------------------------------------------------------- FUSED pack + gc0, grouped-3 pipeline (7 barriers instead of 21)
__global__ __launch_bounds__(256) void k_adjfuse(
    const float* __restrict__ adj,
    unsigned char* __restrict__ adjP,
    const unsigned char* __restrict__ y1in,
    const unsigned short* __restrict__ x,
    const unsigned short* __restrict__ wp0,
    const unsigned short* __restrict__ wp1n,
    unsigned char* __restrict__ y1out,
    const float* __restrict__ posg,
    unsigned short* __restrict__ xnext)
{
  __shared__ __align__(16) unsigned char abuf[2][6144];
  __shared__ unsigned short xbuf[16][168];
  int rb = blockIdx.x, b = blockIdx.y;
  int t = threadIdx.x, w = t >> 6, lane = t & 63;
  int l15 = lane & 15, l4 = lane >> 4;
  int r = t >> 4, kseg = t & 15;
  int grow = rb*16 + r;
  bool rv = grow < NVRT;
  const float* arow = adj + ((size_t)b*NVRT + (rv ? grow : 0))*NVRT;
  unsigned char* tb = adjP + (((size_t)b*NRB16 + rb)*NKT8) * 2048;
  int tslot = 128*r + 8*(kseg ^ r);
  const unsigned char* yb = y1in + (size_t)b * YO;

  f32x4 acc[2], accW[2];
  acc[0] = (f32x4){0,0,0,0};  acc[1] = (f32x4){0,0,0,0};
  accW[0] = (f32x4){0,0,0,0}; accW[1] = (f32x4){0,0,0,0};

  float v[2][3][8];

  auto loadf32 = [&](int ktg, float* vv){
    int gk = ktg*128 + kseg*8;
    if (rv && gk + 8 <= NVRT){
      float4 f0 = *(const float4*)(arow + gk);
      float4 f1 = *(const float4*)(arow + gk + 4);
      vv[0]=f0.x; vv[1]=f0.y; vv[2]=f0.z; vv[3]=f0.w;
      vv[4]=f1.x; vv[5]=f1.y; vv[6]=f1.z; vv[7]=f1.w;
    } else if (rv){
#pragma unroll
      for (int e = 0; e < 8; e++){ int k = gk + e; vv[e] = (k < NVRT) ? arow[k] : 0.f; }
    } else {
#pragma unroll
      for (int e = 0; e < 8; e++) vv[e] = 0.f;
    }
  };

  // prologue: load group 0, prefill xbuf, w0 GEMM (hides load-0 flight)
#pragma unroll
  for (int j = 0; j < 3; j++) loadf32(j, v[0][j]);

  if (t < 48){
    int r16 = t / 3, c = t - r16*3;
    int g2 = rb*16 + r16;
    xbuf[r16][c] = (g2 < NVRT) ? f2bf(posg[((size_t)b*NVRT + g2)*3 + c]) : 0;
  }
  {
    int r16 = t >> 4, c0 = 131 + (t & 15);
    xbuf[r16][c0] = 0;
    if (c0 + 16 < 168) xbuf[r16][c0 + 16] = 0;
    if (c0 + 32 < 168) xbuf[r16][c0 + 32] = 0;
  }

  const unsigned short* xr = x + ((size_t)b*MP + rb*16 + l15)*288 + l4*8;
#pragma unroll
  for (int kb = 0; kb < 288; kb += 32){
    bf16x8 ax = *(const bf16x8*)(xr + kb);
    size_t bo = ((size_t)((kb>>3) + l4)*128 + w*32 + l15)*8;
    MFMA16(accW[0], ax, *(const bf16x8*)(wp0 + bo));
    MFMA16(accW[1], ax, *(const bf16x8*)(wp0 + bo + 128));
  }

  // publish group 0 into abuf[0] + adjP; load group 1
#pragma unroll
  for (int j = 0; j < 3; j++){
    unsigned long long q = 0;
#pragma unroll
    for (int e = 0; e < 8; e++)
      q |= (unsigned long long)f2e4m3(v[0][j][e] * 1024.f) << (8*e);
    *(unsigned long long*)(&abuf[0][j*2048 + tslot]) = q;
    *(unsigned long long*)(tb + (size_t)j*2048 + tslot) = q;
  }
#pragma unroll
  for (int j = 0; j < 3; j++) loadf32(3 + j, v[1][j]);
  __syncthreads();

  // main: 7 groups, one barrier each
#pragma unroll
  for (int g = 0; g < 7; ++g){
    const int cur = g & 1;
    const unsigned char* ab = &abuf[cur][0];
#pragma unroll
    for (int j = 0; j < 3; j++){
      int ktg = 3*g + j;
#pragma unroll
      for (int sel = 0; sel < 2; sel++)
#pragma unroll
        for (int ks = 0; ks < 2; ks++){
          int koct = sel*8 + ks*4 + l4;
          i64 a = *(const i64*)(ab + j*2048 + 128*l15 + 8*(koct ^ l15));
          const unsigned char* bp = yb + ((size_t)(ktg*16 + koct)*128 + w*32 + l15)*8;
          MFMA8(acc[0], a, *(const i64*)bp);
          MFMA8(acc[1], a, *(const i64*)(bp + 128));
        }
    }
    if (g < 6){
      // cvt + publish group g+1 (data loaded last phase) into abuf[cur^1]
#pragma unroll
      for (int j = 0; j < 3; j++){
        unsigned long long q = 0;
#pragma unroll
        for (int e = 0; e < 8; e++)
          q |= (unsigned long long)f2e4m3(v[cur^1][j][e] * 1024.f) << (8*e);
        *(unsigned long long*)(&abuf[cur^1][j*2048 + tslot]) = q;
        *(unsigned long long*)(tb + (size_t)(3*(g+1) + j)*2048 + tslot) = q;
      }
      if (g < 5){
#pragma unroll
        for (int j = 0; j < 3; j++) loadf32(3*(g+2) + j, v[cur][j]);
      }
    }
    __syncthreads();
  }

#pragma unroll
  for (int cf = 0; cf < 2; cf++){
    int col = w*32 + cf*16 + l15;
#pragma unroll
    for (int rr = 0; rr < 4; rr++){
      int row16 = l4*4 + rr;
      int row = rb*16 + row16;
      float vv = fmaxf(accW[cf][rr] + acc[cf][rr] * 0.0009765625f, 0.f);
      unsigned short hb = f2bf(vv);
      if (row < NVRT) xnext[((size_t)b*MP + row)*160 + 3 + col] = hb;
      xbuf[row16][3 + col] = hb;
    }
  }
  __syncthreads();

  // fused NEXT-layer y1: y1out = fp8(xbuf @ wp1n), K=160
  f32x4 accY[2];
  accY[0] = (f32x4){0,0,0,0}; accY[1] = (f32x4){0,0,0,0};
#pragma unroll
  for (int ks = 0; ks < 5; ks++){
    bf16x8 a = *(const bf16x8*)(&xbuf[l15][ks*32 + l4*8]);
    size_t bo = ((size_t)(ks*4 + l4)*128 + w*32 + l15)*8;
    MFMA16(accY[0], a, *(const bf16x8*)(wp1n + bo));
    MFMA16(accY[1], a, *(const bf16x8*)(wp1n + bo + 128));
  }
  unsigned char* yo = y1out + (size_t)b * YO;
#pragma unroll
  for (int cf = 0; cf < 2; cf++){
    int col = w*32 + cf*16 + l15;
    int orow0 = rb*16 + l4*4;
    unsigned qq = f2e4m3(accY[cf][0]) | (f2e4m3(accY[cf][1]) << 8)
                | (f2e4m3(accY[cf][2]) << 16) | (f2e4m3(accY[cf][3]) << 24);
    *(unsigned*)(yo + ((size_t)(orow0 >> 3) * 128 + col) * 8 + (orow0 & 7)) = qq;
  }
}

// ---------------------------------------------------------------- h = relu(x@w0 + adj@y1/1024); MEGA-STAGED fp8 adj GEMM (1 barrier drain)
// EPI=0: writes xnext + fused NEXT-layer y1; EPI=1: out_feat + lin1 head
template<int EPI, int KX>
__global__ __launch_bounds__(256) void k_adj8(
    const unsigned char* __restrict__ adjP,
    const unsigned char* __restrict__ y1in,
    const unsigned short* __restrict__ x,
    const unsigned short* __restrict__ wp0,
    const unsigned short* __restrict__ wp1n,
    unsigned char* __restrict__ y1out,
    const float* __restrict__ posg,
    unsigned short* __restrict__ xnext,
    float* __restrict__ outf,
    const float* __restrict__ wl1, const float* __restrict__ bl1,
    float* __restrict__ opos)
{
  __shared__ __align__(16) unsigned char abuf[NKT8 * 2048];
  __shared__ unsigned short xbuf[EPI == 0 ? 16 : 1][168];
  __shared__ float hbuf[EPI == 1 ? 16 : 1][128];
  int rb = blockIdx.x, b = blockIdx.y;
  int t = threadIdx.x, w = t >> 6, lane = t & 63;
  int l15 = lane & 15, l4 = lane >> 4;
  const unsigned char* tb = adjP + (((size_t)b*NRB16 + rb)*NKT8) * 2048;
  const unsigned char* yb = y1in + (size_t)b * YO;

  f32x4 acc[2], accW[2];
  acc[0] = (f32x4){0,0,0,0};  acc[1] = (f32x4){0,0,0,0};
  accW[0] = (f32x4){0,0,0,0}; accW[1] = (f32x4){0,0,0,0};

  // stage ALL 21 tiles (42 KB) — single drain at the barrier below
  if (w < 2){
#pragma unroll
    for (int kt = 0; kt < NKT8; ++kt)
      gload_lds16(tb + (size_t)kt*2048 + w*1024 + lane*16, &abuf[kt*2048 + w*1024]);
  }

  if (EPI == 0){
    if (t < 48){
      int r16 = t / 3, c = t - r16*3;
      int grow = rb*16 + r16;
      xbuf[r16][c] = (grow < NVRT) ? f2bf(posg[((size_t)b*NVRT + grow)*3 + c]) : 0;
    }
    {
      int r16 = t >> 4, c0 = 131 + (t & 15);
      xbuf[r16][c0] = 0;
      if (c0 + 16 < 168) xbuf[r16][c0 + 16] = 0;
      if (c0 + 32 < 168) xbuf[r16][c0 + 32] = 0;
    }
  }

  // fused x @ w0 (register-only; runs while the DMA stage is in flight)
  const unsigned short* xr = x + ((size_t)b*MP + rb*16 + l15)*KX + l4*8;
#pragma unroll
  for (int kb = 0; kb < KX; kb += 32){
    bf16x8 ax = *(const bf16x8*)(xr + kb);
    size_t bo = ((size_t)((kb>>3) + l4)*128 + w*32 + l15)*8;
    MFMA16(accW[0], ax, *(const bf16x8*)(wp0 + bo));
    MFMA16(accW[1], ax, *(const bf16x8*)(wp0 + bo + 128));
  }

  __syncthreads();   // ONE drain: all 21 tiles now valid

  // barrier-free MFMA stream over all tiles
#pragma unroll 3
  for (int kt = 0; kt < NKT8; ++kt){
    const unsigned char* ab = &abuf[kt*2048];
#pragma unroll
    for (int sel = 0; sel < 2; sel++){
#pragma unroll
      for (int ks = 0; ks < 2; ks++){
        int koct = sel*8 + ks*4 + l4;
        i64 a = *(const i64*)(ab + 128*l15 + 8*(koct ^ l15));
        const unsigned char* bp = yb + ((size_t)(kt*16 + koct)*128 + w*32 + l15)*8;
        MFMA8(acc[0], a, *(const i64*)bp);
        MFMA8(acc[1], a, *(const i64*)(bp + 128));
      }
    }
  }

#pragma unroll
  for (int cf = 0; cf < 2; cf++){
    int col = w*32 + cf*16 + l15;
#pragma unroll
    for (int r = 0; r < 4; r++){
      int row16 = l4*4 + r;
      int row = rb*16 + row16;
      float v = fmaxf(accW[cf][r] + acc[cf][r] * 0.0009765625f, 0.f);
      if (EPI == 0){
        unsigned short hb = f2bf(v);
        if (row < NVRT) xnext[((size_t)b*MP + row)*160 + 3 + col] = hb;
        xbuf[row16][3 + col] = hb;
      } else {
        if (row < NVRT) outf[((size_t)b*NVRT + row)*128 + col] = v;
        hbuf[row16][col] = v;
      }
    }
  }
  __syncthreads();

  if (EPI == 0){
    f32x4 accY[2];
    accY[0] = (f32x4){0,0,0,0}; accY[1] = (f32x4){0,0,0,0};
#pragma unroll
    for (int ks = 0; ks < 5; ks++){
      bf16x8 a = *(const bf16x8*)(&xbuf[l15][ks*32 + l4*8]);
      size_t bo = ((size_t)(ks*4 + l4)*128 + w*32 + l15)*8;
      MFMA16(accY[0], a, *(const bf16x8*)(wp1n + bo));
      MFMA16(accY[1], a, *(const bf16x8*)(wp1n + bo + 128));
    }
    unsigned char* yo = y1out + (size_t)b * YO;
#pragma unroll
    for (int cf = 0; cf < 2; cf++){
      int col = w*32 + cf*16 + l15;
      int orow0 = rb*16 + l4*4;
      unsigned q = f2e4m3(accY[cf][0]) | (f2e4m3(accY[cf][1]) << 8)
                 | (f2e4m3(accY[cf][2]) << 16) | (f2e4m3(accY[cf][3]) << 24);
      *(unsigned*)(yo + ((size_t)(orow0 >> 3) * 128 + col) * 8 + (orow0 & 7)) = q;
    }
  } else {
#pragma unroll
    for (int rr = 0; rr < 4; rr++){
      int row16 = w*4 + rr;
      int grow = rb*16 + row16;
      if (grow < NVRT){
        int c0 = lane * 2;
        float v0 = hbuf[row16][c0], v1 = hbuf[row16][c0+1];
        float p[3];
#pragma unroll
        for (int j = 0; j < 3; j++){
          p[j] = v0 * wl1[c0*3 + j] + v1 * wl1[c0*3 + 3 + j];
#pragma unroll
          for (int off = 1; off < 64; off <<= 1)
            p[j] += __shfl_xor(p[j], off);
        }
        if (lane == 0){
          size_t po = ((size_t)b * NVRT + grow) * 3;
#pragma unroll
          for (int j = 0; j < 3; j++)
            opos[po + j] = posg[po + j] + tanhf(p[j] + bl1[j]);
        }
      }
    }
  }
}

// ================================================================ host
extern "C" void kernel_launch(void* const* d_in, const int* in_sizes, int n_in,
                              void* d_out, int out_size, void* d_ws, size_t ws_size,
                              hipStream_t stream)
{
  const float* conv[4] = {(const float*)d_in[0], (const float*)d_in[1],
                          (const float*)d_in[2], (const float*)d_in[3]};
  const float* adj   = (const float*)d_in[4];
  const float* pos   = (const float*)d_in[5];
  const float* vfeat = (const float*)d_in[6];
  const float* wlin0 = (const float*)d_in[7];
  const float* blin0 = (const float*)d_in[8];
  const float* gw[6] = {(const float*)d_in[9],  (const float*)d_in[10],
                        (const float*)d_in[11], (const float*)d_in[12],
                        (const float*)d_in[13], (const float*)d_in[14]};
  const float* wlin1 = (const float*)d_in[15];
  const float* blin1 = (const float*)d_in[16];

  char* ws = (char*)d_ws;
  size_t off = 0;
  auto take = [&](size_t bytes)->char* {
    char* p = ws + off;
    off += (bytes + 255) & ~(size_t)255;
    return p;
  };
  unsigned short* G    = (unsigned short*)take(G_TOT * 2);
  unsigned char*  adjP = (unsigned char*)take((size_t)NB*NRB16*NKT8*2048);
  unsigned short* wl0p = (unsigned short*)take((size_t)3840*128*2);
  unsigned short* w0p0 = (unsigned short*)take((size_t)288*128*2);
  unsigned short* w1p0 = (unsigned short*)take((size_t)288*128*2);
  unsigned short* w0p1 = (unsigned short*)take((size_t)160*128*2);
  unsigned short* w1p1 = (unsigned short*)take((size_t)160*128*2);
  unsigned short* w0p2 = (unsigned short*)take((size_t)160*128*2);
  unsigned short* w1p2 = (unsigned short*)take((size_t)160*128*2);
  unsigned short* vf   = (unsigned short*)take((size_t)NB*MP*288*2);
  unsigned short* x1   = (unsigned short*)take((size_t)NB*MP*160*2);
  unsigned short* x2   = (unsigned short*)take((size_t)NB*MP*160*2);
  unsigned char*  y1A  = (unsigned char*)take((size_t)NB*YO);
  unsigned char*  y1B  = (unsigned char*)take((size_t)NB*YO);

  float* out_pos  = (float*)d_out;
  float* out_feat = out_pos + (size_t)NB*NVRT*3;

  // 1. weight packing
  PWArgs pw;
  pw.src[0]=wlin0; pw.dst[0]=wl0p; pw.ksrc[0]=3840; pw.nsrc[0]=128;
  pw.src[1]=gw[0]; pw.dst[1]=w0p0; pw.ksrc[1]=259;  pw.nsrc[1]=131;
  pw.src[2]=gw[1]; pw.dst[2]=w1p0; pw.ksrc[2]=259;  pw.nsrc[2]=131;
  pw.src[3]=gw[2]; pw.dst[3]=w0p1; pw.ksrc[3]=131;  pw.nsrc[3]=128;
  pw.src[4]=gw[3]; pw.dst[4]=w1p1; pw.ksrc[4]=131;  pw.nsrc[4]=128;
  pw.src[5]=gw[4]; pw.dst[5]=w0p2; pw.ksrc[5]=131;  pw.nsrc[5]=128;
  pw.src[6]=gw[5]; pw.dst[6]=w1p2; pw.ksrc[6]=131;  pw.nsrc[6]=128;
  k_packw_all<<<2528, 256, 0, stream>>>(pw);
  // 2. fused conv transpose + pixel projection G = ft^T @ w_lin0
  k_gproj2<<<1056, 256, 0, stream>>>(conv[0], conv[1], conv[2], conv[3], wl0p, G);
  // 3. gather-blend + vf base + pads + y1 tail-zero (both buffers)
  k_prep2<<<dim3(MP/4, NB), 256, 0, stream>>>(vfeat, pos, G, blin0, vf, x1, x2, y1A, y1B);
  // 4. first y1 (from vf)
  k_y1<288><<<dim3(NRB2, NB), 256, 0, stream>>>(vf, w1p0, y1A);
  // 5. FUSED adjacency pack + gc0 (reads raw f32 adj once; emits adjP, x1, y1B)
  k_adjfuse<<<dim3(NRB16, NB), 256, 0, stream>>>(adj, adjP, y1A, vf, w0p0, w1p1, y1B, pos, x1);
  // 6-7. gc1, gc2
  k_adj8<0,160><<<dim3(NRB16, NB), 256, 0, stream>>>(adjP, y1B, x1, w0p1, w1p2, y1A, pos,
                                                     x2, nullptr, nullptr, nullptr, nullptr);
  k_adj8<1,160><<<dim3(NRB16, NB), 256, 0, stream>>>(adjP, y1A, x2, w0p2, nullptr, nullptr, pos,
                                                     nullptr, out_feat, wlin1, blin1, out_pos);
  (void)in_sizes; (void)n_in; (void)out_size; (void)ws_size;
}

// Round 12
// 262.707 us; speedup vs baseline: 1.0417x; 1.0417x over previous
//
#include <hip/hip_runtime.h>
#include <hip/hip_bf16.h>

typedef __attribute__((ext_vector_type(8))) short bf16x8;
typedef __attribute__((ext_vector_type(4))) float f32x4;
typedef long long i64;

static __device__ __forceinline__ float bflo(unsigned v){ return __uint_as_float(v << 16); }
static __device__ __forceinline__ float bfhi(unsigned v){ return __uint_as_float(v & 0xffff0000u); }
static __device__ __forceinline__ unsigned short f2bf(float f){
  unsigned u = __float_as_uint(f);
  u += 0x7FFFu + ((u >> 16) & 1u);
  return (unsigned short)(u >> 16);
}
// OCP e4m3fn encode, RNE, saturating (software fallback)
static __device__ __forceinline__ unsigned f2e4m3(float x){
  unsigned b = __float_as_uint(x);
  unsigned s = (b >> 31) << 7;
  b &= 0x7fffffffu;
  if (b >= 0x43e80000u) return s | 0x7eu;
  if (b < 0x3c800000u)
    return s | (unsigned)rintf(__uint_as_float(b) * 512.f);
  unsigned b2 = b + 0x7ffffu + ((b >> 20) & 1u);
  return s | (((b2 >> 23) - 120u) << 3) | ((b2 >> 20) & 7u);
}
// 4x f32 -> packed fp8 e4m3 (HW convert when available)
static __device__ __forceinline__ unsigned pk4_e4m3(float a, float b, float c, float d){
#if __has_builtin(__builtin_amdgcn_cvt_pk_fp8_f32)
  unsigned r = 0;
  r = (unsigned)__builtin_amdgcn_cvt_pk_fp8_f32(a, b, (int)r, false);
  r = (unsigned)__builtin_amdgcn_cvt_pk_fp8_f32(c, d, (int)r, true);
  return r;
#else
  return f2e4m3(a) | (f2e4m3(b) << 8) | (f2e4m3(c) << 16) | (f2e4m3(d) << 24);
#endif
}
static __device__ __forceinline__ void gload_lds16(const void* g, void* l){
  __builtin_amdgcn_global_load_lds((const __attribute__((address_space(1))) unsigned int*)g,
                                   (__attribute__((address_space(3))) unsigned int*)l, 16, 0, 0);
}

#define MFMA16(acc, a, b) (acc) = __builtin_amdgcn_mfma_f32_16x16x32_bf16((a),(b),(acc),0,0,0)
#define MFMA8(acc, a, b)  (acc) = __builtin_amdgcn_mfma_f32_16x16x32_fp8_fp8((a),(b),(acc),0,0,0)

#define NB    8
#define NVRT  2562
#define MP    2624     /* rows padded to 82*32 = 164*16 */
#define NRB2  82
#define NRB16 164      /* 16-row blocks (adj) */
#define NKT8  21       /* K tiles of 128 over 2688 */
#define KOCT  336
#define YO    ((size_t)KOCT*128*8)   /* y1p8 per-batch bytes */

// pixel-projection buffer bases (elements), layout [B*HW][128] bf16 per map
#define G_B0 0ul
#define G_B1 3211264ul
#define G_B2 4014080ul
#define G_B3 4214784ul
#define G_TOT 4264960ul

// ---------------------------------------------------------------- unified weight pack: 7 weights -> [Kp/8][128][8] bf16
struct PWArgs {
  const float* src[7];
  unsigned short* dst[7];
  int ksrc[7], nsrc[7];
};
__global__ void k_packw_all(PWArgs a)
{
  const int cb[8] = {0,491520,528384,565248,585728,606208,626688,647168};
  int g = blockIdx.x * 256 + threadIdx.x;
#pragma unroll
  for (int s = 0; s < 7; s++){
    if (g >= cb[s] && g < cb[s+1]){
      int li = g - cb[s];
      int k = li >> 7, c = li & 127;
      int ks = a.ksrc[s], ns = a.nsrc[s];
      float v = (k < ks) ? a.src[s][(size_t)k * ns + c] : 0.f;
      a.dst[s][((size_t)(k >> 3) * 128 + c) * 8 + (k & 7)] = f2bf(v);
    }
  }
}

// ---------------------------------------------------------------- fused conv-read + pixel projection: G_m = ftT_m @ W_m
__global__ __launch_bounds__(256) void k_gproj2(
    const float* __restrict__ c0m, const float* __restrict__ c1m,
    const float* __restrict__ c2m, const float* __restrict__ c3m,
    const unsigned short* __restrict__ wp,
    unsigned short* __restrict__ G)
{
  __shared__ f32x4 red[3][1024];
  int bx = blockIdx.x;
  int m, b, tile;
  if (bx < 784)      { m = 0; b = bx / 98;  tile = bx - b*98; }
  else if (bx < 984) { int l = bx-784;  m = 1; b = l / 25; tile = l - b*25; }
  else if (bx < 1040){ int l = bx-984;  m = 2; b = l / 7;  tile = l - b*7; }
  else               { int l = bx-1040; m = 3; b = l >> 1; tile = l & 1; }
  int C  = 256 << m;
  int HW = (m==0)?3136:(m==1)?784:(m==2)?196:49;
  const float* src = ((m==0)?c0m:(m==1)?c1m:(m==2)?c2m:c3m) + (size_t)b * C * HW;
  size_t gb = ((m==0)?G_B0:(m==1)?G_B1:(m==2)?G_B2:G_B3) + (size_t)b * HW * 128;
  int ko8 = (m==0)?0:(m==1)?32:(m==2)?96:224;

  int t = threadIdx.x, w = t >> 6, lane = t & 63;
  int l15 = lane & 15, l4 = lane >> 4;
  int hw0 = tile * 32;
  int ar0 = min(hw0 + l15, HW - 1);
  int ar1 = min(hw0 + 16 + l15, HW - 1);

  f32x4 acc[2][8];
#pragma unroll
  for (int i = 0; i < 2; i++)
#pragma unroll
    for (int j = 0; j < 8; j++) acc[i][j] = (f32x4){0,0,0,0};

  int kq = C >> 2;
  int kbeg = w * kq, klim = kbeg + kq;
  for (int kb = kbeg; kb < klim; kb += 32){
    bf16x8 a0, a1;
#pragma unroll
    for (int j = 0; j < 8; j++){
      int cc = kb + l4*8 + j;
      a0[j] = (short)f2bf(src[(size_t)cc * HW + ar0]);
      a1[j] = (short)f2bf(src[(size_t)cc * HW + ar1]);
    }
    size_t bo = ((size_t)(ko8 + (kb>>3) + l4) * 128 + l15) * 8;
#pragma unroll
    for (int cf = 0; cf < 8; cf++){
      bf16x8 bb = *(const bf16x8*)(wp + bo + cf*128);
      MFMA16(acc[0][cf], a0, bb);
      MFMA16(acc[1][cf], a1, bb);
    }
  }

  if (w){
#pragma unroll
    for (int rf = 0; rf < 2; rf++)
#pragma unroll
      for (int cf = 0; cf < 8; cf++)
        red[w-1][(rf*8+cf)*64 + lane] = acc[rf][cf];
  }
  __syncthreads();
  if (!w){
#pragma unroll
    for (int rf = 0; rf < 2; rf++)
#pragma unroll
      for (int cf = 0; cf < 8; cf++){
        int i = (rf*8+cf)*64 + lane;
        f32x4 s = acc[rf][cf] + red[0][i] + red[1][i] + red[2][i];
        int col = cf*16 + l15;
#pragma unroll
        for (int r = 0; r < 4; r++){
          int hw = hw0 + rf*16 + l4*4 + r;
          if (hw < HW) G[gb + (size_t)hw*128 + col] = f2bf(s[r]);
        }
      }
  }
}

// ---------------------------------------------------------------- prep: gather-blend from G + vf base + x1/x2 pads + y1 tail-zero (both buffers)
__global__ void k_prep2(const float* __restrict__ vfeat, const float* __restrict__ pos,
                        const unsigned short* __restrict__ G,
                        const float* __restrict__ bias,
                        unsigned short* __restrict__ vf,
                        unsigned short* __restrict__ x1,
                        unsigned short* __restrict__ x2,
                        unsigned char* __restrict__ y1A,
                        unsigned char* __restrict__ y1B)
{
  int b = blockIdx.y;
  if (blockIdx.x == 0){
    unsigned long long* za = (unsigned long long*)(y1A + (size_t)b*YO + (size_t)328*128*8);
    unsigned long long* zb = (unsigned long long*)(y1B + (size_t)b*YO + (size_t)328*128*8);
    int i = threadIdx.x;
#pragma unroll
    for (int j = 0; j < 4; j++){ za[i*4+j] = 0; zb[i*4+j] = 0; }
  }
  int row = blockIdx.x * 4 + (threadIdx.x >> 6);
  int lane = threadIdx.x & 63;
  size_t vfo = ((size_t)b * MP + row) * 288;
  size_t xo  = ((size_t)b * MP + row) * 160;
  if (row < NVRT){
    size_t src = (size_t)b * NVRT + row;
    float px = fminf(fmaxf(pos[src*3 + 0], -1.f), 1.f);
    float py = fminf(fmaxf(pos[src*3 + 1], -1.f), 1.f);
    int c0 = lane * 2;
    float s0 = bias[c0], s1 = bias[c0 + 1];
#pragma unroll
    for (int m = 0; m < 4; m++){
      int W = 56 >> m;
      int HW = W * W;
      size_t gb = (m==0)?G_B0:(m==1)?G_B1:(m==2)?G_B2:G_B3;
      float gx = (px + 1.f) * 0.5f * (float)(W - 1);
      float gy = (py + 1.f) * 0.5f * (float)(W - 1);
      int x0 = (int)floorf(gx), y0 = (int)floorf(gy);
      float wx = gx - (float)x0, wy = gy - (float)y0;
      int x1i = min(x0 + 1, W - 1), y1i = min(y0 + 1, W - 1);
      const unsigned short* g = G + gb + (size_t)b * HW * 128;
      unsigned v00 = *(const unsigned*)(g + ((size_t)(y0 *W + x0 ))*128 + c0);
      unsigned v01 = *(const unsigned*)(g + ((size_t)(y0 *W + x1i))*128 + c0);
      unsigned v10 = *(const unsigned*)(g + ((size_t)(y1i*W + x0 ))*128 + c0);
      unsigned v11 = *(const unsigned*)(g + ((size_t)(y1i*W + x1i))*128 + c0);
      float w00 = (1.f-wx)*(1.f-wy), w01 = wx*(1.f-wy);
      float w10 = (1.f-wx)*wy,       w11 = wx*wy;
      s0 += w00*bflo(v00) + w01*bflo(v01) + w10*bflo(v10) + w11*bflo(v11);
      s1 += w00*bfhi(v00) + w01*bfhi(v01) + w10*bfhi(v10) + w11*bfhi(v11);
    }
    vf[vfo + 131 + c0]     = f2bf(s0);
    vf[vfo + 131 + c0 + 1] = f2bf(s1);
    float2 fv = *(const float2*)(vfeat + src*128 + c0);
    vf[vfo + c0]     = f2bf(fv.x);
    vf[vfo + c0 + 1] = f2bf(fv.y);
    if (lane < 3){
      unsigned short v = f2bf(pos[src*3 + lane]);
      vf[vfo + 128 + lane] = v;
      x1[xo + lane] = v;
      x2[xo + lane] = v;
    }
    if (lane >= 32 && lane < 61) vf[vfo + 259 + (lane - 32)] = 0;
    if (lane < 29){ x1[xo + 131 + lane] = 0; x2[xo + 131 + lane] = 0; }
  } else {
    for (int c = lane; c < 288; c += 64) vf[vfo + c] = 0;
    for (int c = lane; c < 160; c += 64){ x1[xo + c] = 0; x2[xo + c] = 0; }
  }
}

// ---------------------------------------------------------------- pack adjacency f32 -> fp8 e4m3 (x1024) MFMA tiles (HW cvt)
// tile (b, rb16, kt128) = 2048 B; byte = 128*row + 8*(koct ^ row)  (XOR involution)
__global__ void k_adjpack8(const float* __restrict__ adj, unsigned char* __restrict__ adjP)
{
  int kt = blockIdx.x, rb = blockIdx.y, b = blockIdx.z;
  int t = threadIdx.x;
  int r = t >> 4, kseg = t & 15;
  int grow = rb*16 + r, gk = kt*128 + kseg*8;
  float v[8];
  if (grow < NVRT && gk + 8 <= NVRT){
    const float4* p = (const float4*)(adj + ((size_t)b*NVRT + grow)*NVRT + gk);
    float4 f0 = p[0], f1 = p[1];
    v[0]=f0.x; v[1]=f0.y; v[2]=f0.z; v[3]=f0.w;
    v[4]=f1.x; v[5]=f1.y; v[6]=f1.z; v[7]=f1.w;
  } else if (grow < NVRT){
    const float* ap = adj + ((size_t)b*NVRT + grow)*NVRT;
#pragma unroll
    for (int e = 0; e < 8; e++){ int k = gk + e; v[e] = (k < NVRT) ? ap[k] : 0.f; }
  } else {
#pragma unroll
    for (int e = 0; e < 8; e++) v[e] = 0.f;
  }
  unsigned lo = pk4_e4m3(v[0]*1024.f, v[1]*1024.f, v[2]*1024.f, v[3]*1024.f);
  unsigned hi = pk4_e4m3(v[4]*1024.f, v[5]*1024.f, v[6]*1024.f, v[7]*1024.f);
  unsigned long long q = (unsigned long long)lo | ((unsigned long long)hi << 32);
  unsigned char* tb = adjP + (((size_t)b*NRB16 + rb)*NKT8 + kt) * 2048;
  *(unsigned long long*)(tb + 128*r + 8*(kseg ^ r)) = q;
}

// ---------------------------------------------------------------- y1p8 = fp8(x @ w1)  (first gc only)
template<int KX>
__global__ __launch_bounds__(256) void k_y1(
    const unsigned short* __restrict__ x,
    const unsigned short* __restrict__ wp1,
    unsigned char* __restrict__ y1p8)
{
  int b = blockIdx.y, rb = blockIdx.x * 32;
  int t = threadIdx.x, wave = t >> 6, lane = t & 63;
  int rf = wave & 1, ch = wave >> 1;
  int l15 = lane & 15, l4 = lane >> 4;
  f32x4 a1[4];
#pragma unroll
  for (int c = 0; c < 4; c++) a1[c] = (f32x4){0,0,0,0};
  int row = rb + rf*16 + l15;
  const unsigned short* xp = x + ((size_t)b * MP + row) * KX + l4 * 8;
#pragma unroll
  for (int kb = 0; kb < KX; kb += 32){
    bf16x8 a = *(const bf16x8*)(xp + kb);
    size_t bo = ((size_t)((kb>>3) + l4) * 128 + ch*64 + l15) * 8;
#pragma unroll
    for (int c = 0; c < 4; c++){
      bf16x8 b1 = *(const bf16x8*)(wp1 + bo + c*128);
      MFMA16(a1[c], a, b1);
    }
  }
  unsigned char* yb = y1p8 + (size_t)b * YO;
#pragma unroll
  for (int c = 0; c < 4; c++){
    int col = ch*64 + c*16 + l15;
    int orow0 = rb + rf*16 + l4*4;
    unsigned q = pk4_e4m3(a1[c][0], a1[c][1], a1[c][2], a1[c][3]);
    *(unsigned*)(yb + ((size_t)(orow0 >> 3) * 128 + col) * 8 + (orow0 & 7)) = q;
  }
}

// ---------------------------------------------------------------- h = relu(x@w0 + adj@y1/1024); LDS-staged fp8 adj GEMM + fused w0 GEMM
// EPI=0: writes xnext + fused NEXT-layer y1 (y1out, K=160); EPI=1: out_feat + lin1 head
template<int EPI, int KX>
__global__ __launch_bounds__(256) void k_adj8(
    const unsigned char* __restrict__ adjP,
    const unsigned char* __restrict__ y1in,
    const unsigned short* __restrict__ x,
    const unsigned short* __restrict__ wp0,
    const unsigned short* __restrict__ wp1n,
    unsigned char* __restrict__ y1out,
    const float* __restrict__ posg,
    unsigned short* __restrict__ xnext,
    float* __restrict__ outf,
    const float* __restrict__ wl1, const float* __restrict__ bl1,
    float* __restrict__ opos)
{
  __shared__ __align__(16) unsigned char abuf[2][2048];
  __shared__ unsigned short xbuf[EPI == 0 ? 16 : 1][168];
  __shared__ float hbuf[EPI == 1 ? 16 : 1][128];
  int rb = blockIdx.x, b = blockIdx.y;
  int t = threadIdx.x, w = t >> 6, lane = t & 63;
  int l15 = lane & 15, l4 = lane >> 4;
  const unsigned char* tb = adjP + (((size_t)b*NRB16 + rb)*NKT8) * 2048;
  const unsigned char* yb = y1in + (size_t)b * YO;

  f32x4 acc[2], accW[2];
  acc[0] = (f32x4){0,0,0,0};  acc[1] = (f32x4){0,0,0,0};
  accW[0] = (f32x4){0,0,0,0}; accW[1] = (f32x4){0,0,0,0};

  auto stage = [&](int kt, int bufi){
    if (w < 2)
      gload_lds16(tb + (size_t)kt*2048 + w*1024 + lane*16, &abuf[bufi][w*1024]);
  };

  stage(0, 0);

  if (EPI == 0){
    if (t < 48){
      int r16 = t / 3, c = t - r16*3;
      int grow = rb*16 + r16;
      xbuf[r16][c] = (grow < NVRT) ? f2bf(posg[((size_t)b*NVRT + grow)*3 + c]) : 0;
    }
    {
      int r16 = t >> 4, c0 = 131 + (t & 15);
      xbuf[r16][c0] = 0;
      if (c0 + 16 < 168) xbuf[r16][c0 + 16] = 0;
      if (c0 + 32 < 168) xbuf[r16][c0 + 32] = 0;
    }
  }

  const unsigned short* xr = x + ((size_t)b*MP + rb*16 + l15)*KX + l4*8;
#pragma unroll
  for (int kb = 0; kb < KX; kb += 32){
    bf16x8 ax = *(const bf16x8*)(xr + kb);
    size_t bo = ((size_t)((kb>>3) + l4)*128 + w*32 + l15)*8;
    MFMA16(accW[0], ax, *(const bf16x8*)(wp0 + bo));
    MFMA16(accW[1], ax, *(const bf16x8*)(wp0 + bo + 128));
  }

  __syncthreads();

  for (int kt = 0; kt < NKT8; ++kt){
    int cur = kt & 1;
    if (kt < NKT8-1) stage(kt+1, cur ^ 1);
    const unsigned char* ab = &abuf[cur][0];
#pragma unroll
    for (int sel = 0; sel < 2; sel++){
#pragma unroll
      for (int ks = 0; ks < 2; ks++){
        int koct = sel*8 + ks*4 + l4;
        i64 a = *(const i64*)(ab + 128*l15 + 8*(koct ^ l15));
        const unsigned char* bp = yb + ((size_t)(kt*16 + koct)*128 + w*32 + l15)*8;
        i64 b0 = *(const i64*)(bp);
        i64 b1 = *(const i64*)(bp + 128);
        MFMA8(acc[0], a, b0);
        MFMA8(acc[1], a, b1);
      }
    }
    __syncthreads();
  }

#pragma unroll
  for (int cf = 0; cf < 2; cf++){
    int col = w*32 + cf*16 + l15;
#pragma unroll
    for (int r = 0; r < 4; r++){
      int row16 = l4*4 + r;
      int row = rb*16 + row16;
      float v = fmaxf(accW[cf][r] + acc[cf][r] * 0.0009765625f, 0.f);
      if (EPI == 0){
        unsigned short hb = f2bf(v);
        if (row < NVRT) xnext[((size_t)b*MP + row)*160 + 3 + col] = hb;
        xbuf[row16][3 + col] = hb;
      } else {
        if (row < NVRT) outf[((size_t)b*NVRT + row)*128 + col] = v;
        hbuf[row16][col] = v;
      }
    }
  }
  __syncthreads();

  if (EPI == 0){
    f32x4 accY[2];
    accY[0] = (f32x4){0,0,0,0}; accY[1] = (f32x4){0,0,0,0};
#pragma unroll
    for (int ks = 0; ks < 5; ks++){
      bf16x8 a = *(const bf16x8*)(&xbuf[l15][ks*32 + l4*8]);
      size_t bo = ((size_t)(ks*4 + l4)*128 + w*32 + l15)*8;
      MFMA16(accY[0], a, *(const bf16x8*)(wp1n + bo));
      MFMA16(accY[1], a, *(const bf16x8*)(wp1n + bo + 128));
    }
    unsigned char* yo = y1out + (size_t)b * YO;
#pragma unroll
    for (int cf = 0; cf < 2; cf++){
      int col = w*32 + cf*16 + l15;
      int orow0 = rb*16 + l4*4;
      unsigned q = pk4_e4m3(accY[cf][0], accY[cf][1], accY[cf][2], accY[cf][3]);
      *(unsigned*)(yo + ((size_t)(orow0 >> 3) * 128 + col) * 8 + (orow0 & 7)) = q;
    }
  } else {
#pragma unroll
    for (int rr = 0; rr < 4; rr++){
      int row16 = w*4 + rr;
      int grow = rb*16 + row16;
      if (grow < NVRT){
        int c0 = lane * 2;
        float v0 = hbuf[row16][c0], v1 = hbuf[row16][c0+1];
        float p[3];
#pragma unroll
        for (int j = 0; j < 3; j++){
          p[j] = v0 * wl1[c0*3 + j] + v1 * wl1[c0*3 + 3 + j];
#pragma unroll
          for (int off = 1; off < 64; off <<= 1)
            p[j] += __shfl_xor(p[j], off);
        }
        if (lane == 0){
          size_t po = ((size_t)b * NVRT + grow) * 3;
#pragma unroll
          for (int j = 0; j < 3; j++)
            opos[po + j] = posg[po + j] + tanhf(p[j] + bl1[j]);
        }
      }
    }
  }
}

// ================================================================ host
extern "C" void kernel_launch(void* const* d_in, const int* in_sizes, int n_in,
                              void* d_out, int out_size, void* d_ws, size_t ws_size,
                              hipStream_t stream)
{
  const float* conv[4] = {(const float*)d_in[0], (const float*)d_in[1],
                          (const float*)d_in[2], (const float*)d_in[3]};
  const float* adj   = (const float*)d_in[4];
  const float* pos   = (const float*)d_in[5];
  const float* vfeat = (const float*)d_in[6];
  const float* wlin0 = (const float*)d_in[7];
  const float* blin0 = (const float*)d_in[8];
  const float* gw[6] = {(const float*)d_in[9],  (const float*)d_in[10],
                        (const float*)d_in[11], (const float*)d_in[12],
                        (const float*)d_in[13], (const float*)d_in[14]};
  const float* wlin1 = (const float*)d_in[15];
  const float* blin1 = (const float*)d_in[16];

  char* ws = (char*)d_ws;
  size_t off = 0;
  auto take = [&](size_t bytes)->char* {
    char* p = ws + off;
    off += (bytes + 255) & ~(size_t)255;
    return p;
  };
  unsigned short* G    = (unsigned short*)take(G_TOT * 2);
  unsigned char*  adjP = (unsigned char*)take((size_t)NB*NRB16*NKT8*2048);
  unsigned short* wl0p = (unsigned short*)take((size_t)3840*128*2);
  unsigned short* w0p0 = (unsigned short*)take((size_t)288*128*2);
  unsigned short* w1p0 = (unsigned short*)take((size_t)288*128*2);
  unsigned short* w0p1 = (unsigned short*)take((size_t)160*128*2);
  unsigned short* w1p1 = (unsigned short*)take((size_t)160*128*2);
  unsigned short* w0p2 = (unsigned short*)take((size_t)160*128*2);
  unsigned short* w1p2 = (unsigned short*)take((size_t)160*128*2);
  unsigned short* vf   = (unsigned short*)take((size_t)NB*MP*288*2);
  unsigned short* x1   = (unsigned short*)take((size_t)NB*MP*160*2);
  unsigned short* x2   = (unsigned short*)take((size_t)NB*MP*160*2);
  unsigned char*  y1A  = (unsigned char*)take((size_t)NB*YO);
  unsigned char*  y1B  = (unsigned char*)take((size_t)NB*YO);

  float* out_pos  = (float*)d_out;
  float* out_feat = out_pos + (size_t)NB*NVRT*3;

  // 1. weight packing
  PWArgs pw;
  pw.src[0]=wlin0; pw.dst[0]=wl0p; pw.ksrc[0]=3840; pw.nsrc[0]=128;
  pw.src[1]=gw[0]; pw.dst[1]=w0p0; pw.ksrc[1]=259;  pw.nsrc[1]=131;
  pw.src[2]=gw[1]; pw.dst[2]=w1p0; pw.ksrc[2]=259;  pw.nsrc[2]=131;
  pw.src[3]=gw[2]; pw.dst[3]=w0p1; pw.ksrc[3]=131;  pw.nsrc[3]=128;
  pw.src[4]=gw[3]; pw.dst[4]=w1p1; pw.ksrc[4]=131;  pw.nsrc[4]=128;
  pw.src[5]=gw[4]; pw.dst[5]=w0p2; pw.ksrc[5]=131;  pw.nsrc[5]=128;
  pw.src[6]=gw[5]; pw.dst[6]=w1p2; pw.ksrc[6]=131;  pw.nsrc[6]=128;
  k_packw_all<<<2528, 256, 0, stream>>>(pw);
  // 2. fused conv transpose + pixel projection G = ft^T @ w_lin0
  k_gproj2<<<1056, 256, 0, stream>>>(conv[0], conv[1], conv[2], conv[3], wl0p, G);
  // 3. gather-blend + vf base + pads + y1 tail-zero (both buffers)
  k_prep2<<<dim3(MP/4, NB), 256, 0, stream>>>(vfeat, pos, G, blin0, vf, x1, x2, y1A, y1B);
  // 4. first y1 (from vf)
  k_y1<288><<<dim3(NRB2, NB), 256, 0, stream>>>(vf, w1p0, y1A);
  // 5. pack adjacency to fp8 swizzled tiles (x1024, HW convert)
  k_adjpack8<<<dim3(NKT8, NRB16, NB), 256, 0, stream>>>(adj, adjP);
  // 6-8. three graph convs; each adj8<0> also emits the NEXT layer's y1
  k_adj8<0,288><<<dim3(NRB16, NB), 256, 0, stream>>>(adjP, y1A, vf, w0p0, w1p1, y1B, pos,
                                                     x1, nullptr, nullptr, nullptr, nullptr);
  k_adj8<0,160><<<dim3(NRB16, NB), 256, 0, stream>>>(adjP, y1B, x1, w0p1, w1p2, y1A, pos,
                                                     x2, nullptr, nullptr, nullptr, nullptr);
  k_adj8<1,160><<<dim3(NRB16, NB), 256, 0, stream>>>(adjP, y1A, x2, w0p2, nullptr, nullptr, pos,
                                                     nullptr, out_feat, wlin1, blin1, out_pos);
  (void)in_sizes; (void)n_in; (void)out_size; (void)ws_size;
}

// Round 13
// 257.781 us; speedup vs baseline: 1.0616x; 1.0191x over previous
//
#include <hip/hip_runtime.h>
#include <hip/hip_bf16.h>

typedef __attribute__((ext_vector_type(8))) short bf16x8;
typedef __attribute__((ext_vector_type(4))) float f32x4;
typedef long long i64;

static __device__ __forceinline__ float bflo(unsigned v){ return __uint_as_float(v << 16); }
static __device__ __forceinline__ float bfhi(unsigned v){ return __uint_as_float(v & 0xffff0000u); }
static __device__ __forceinline__ unsigned short f2bf(float f){
  unsigned u = __float_as_uint(f);
  u += 0x7FFFu + ((u >> 16) & 1u);
  return (unsigned short)(u >> 16);
}
// OCP e4m3fn encode, RNE, saturating (software fallback)
static __device__ __forceinline__ unsigned f2e4m3(float x){
  unsigned b = __float_as_uint(x);
  unsigned s = (b >> 31) << 7;
  b &= 0x7fffffffu;
  if (b >= 0x43e80000u) return s | 0x7eu;
  if (b < 0x3c800000u)
    return s | (unsigned)rintf(__uint_as_float(b) * 512.f);
  unsigned b2 = b + 0x7ffffu + ((b >> 20) & 1u);
  return s | (((b2 >> 23) - 120u) << 3) | ((b2 >> 20) & 7u);
}
// 4x f32 -> packed fp8 e4m3 (HW convert when available)
static __device__ __forceinline__ unsigned pk4_e4m3(float a, float b, float c, float d){
#if __has_builtin(__builtin_amdgcn_cvt_pk_fp8_f32)
  unsigned r = 0;
  r = (unsigned)__builtin_amdgcn_cvt_pk_fp8_f32(a, b, (int)r, false);
  r = (unsigned)__builtin_amdgcn_cvt_pk_fp8_f32(c, d, (int)r, true);
  return r;
#else
  return f2e4m3(a) | (f2e4m3(b) << 8) | (f2e4m3(c) << 16) | (f2e4m3(d) << 24);
#endif
}
static __device__ __forceinline__ void gload_lds16(const void* g, void* l){
  __builtin_amdgcn_global_load_lds((const __attribute__((address_space(1))) unsigned int*)g,
                                   (__attribute__((address_space(3))) unsigned int*)l, 16, 0, 0);
}

#define MFMA16(acc, a, b) (acc) = __builtin_amdgcn_mfma_f32_16x16x32_bf16((a),(b),(acc),0,0,0)
#define MFMA8(acc, a, b)  (acc) = __builtin_amdgcn_mfma_f32_16x16x32_fp8_fp8((a),(b),(acc),0,0,0)

#define NB    8
#define NVRT  2562
#define MP    2624     /* rows padded to 82*32 = 164*16 */
#define NRB2  82
#define NRB16 164      /* 16-row blocks (adj) */
#define NKT8  21       /* K tiles of 128 over 2688 */
#define KOCT  336
#define YO    ((size_t)KOCT*128*8)   /* y1p8 per-batch bytes */

// pixel-projection buffer bases (elements), layout [B*HW][128] bf16 per map
#define G_B0 0ul
#define G_B1 3211264ul
#define G_B2 4014080ul
#define G_B3 4214784ul
#define G_TOT 4264960ul

// ---------------------------------------------------------------- unified weight pack: 7 weights -> [Kp/8][128][8] bf16
struct PWArgs {
  const float* src[7];
  unsigned short* dst[7];
  int ksrc[7], nsrc[7];
};
__global__ void k_packw_all(PWArgs a)
{
  const int cb[8] = {0,491520,528384,565248,585728,606208,626688,647168};
  int g = blockIdx.x * 256 + threadIdx.x;
#pragma unroll
  for (int s = 0; s < 7; s++){
    if (g >= cb[s] && g < cb[s+1]){
      int li = g - cb[s];
      int k = li >> 7, c = li & 127;
      int ks = a.ksrc[s], ns = a.nsrc[s];
      float v = (k < ks) ? a.src[s][(size_t)k * ns + c] : 0.f;
      a.dst[s][((size_t)(k >> 3) * 128 + c) * 8 + (k & 7)] = f2bf(v);
    }
  }
}

// ---------------------------------------------------------------- fused conv-read + pixel projection: G_m = ftT_m @ W_m
__global__ __launch_bounds__(256) void k_gproj2(
    const float* __restrict__ c0m, const float* __restrict__ c1m,
    const float* __restrict__ c2m, const float* __restrict__ c3m,
    const unsigned short* __restrict__ wp,
    unsigned short* __restrict__ G)
{
  __shared__ f32x4 red[3][1024];
  int bx = blockIdx.x;
  int m, b, tile;
  if (bx < 784)      { m = 0; b = bx / 98;  tile = bx - b*98; }
  else if (bx < 984) { int l = bx-784;  m = 1; b = l / 25; tile = l - b*25; }
  else if (bx < 1040){ int l = bx-984;  m = 2; b = l / 7;  tile = l - b*7; }
  else               { int l = bx-1040; m = 3; b = l >> 1; tile = l & 1; }
  int C  = 256 << m;
  int HW = (m==0)?3136:(m==1)?784:(m==2)?196:49;
  const float* src = ((m==0)?c0m:(m==1)?c1m:(m==2)?c2m:c3m) + (size_t)b * C * HW;
  size_t gb = ((m==0)?G_B0:(m==1)?G_B1:(m==2)?G_B2:G_B3) + (size_t)b * HW * 128;
  int ko8 = (m==0)?0:(m==1)?32:(m==2)?96:224;

  int t = threadIdx.x, w = t >> 6, lane = t & 63;
  int l15 = lane & 15, l4 = lane >> 4;
  int hw0 = tile * 32;
  int ar0 = min(hw0 + l15, HW - 1);
  int ar1 = min(hw0 + 16 + l15, HW - 1);

  f32x4 acc[2][8];
#pragma unroll
  for (int i = 0; i < 2; i++)
#pragma unroll
    for (int j = 0; j < 8; j++) acc[i][j] = (f32x4){0,0,0,0};

  int kq = C >> 2;
  int kbeg = w * kq, klim = kbeg + kq;
  for (int kb = kbeg; kb < klim; kb += 32){
    bf16x8 a0, a1;
#pragma unroll
    for (int j = 0; j < 8; j++){
      int cc = kb + l4*8 + j;
      a0[j] = (short)f2bf(src[(size_t)cc * HW + ar0]);
      a1[j] = (short)f2bf(src[(size_t)cc * HW + ar1]);
    }
    size_t bo = ((size_t)(ko8 + (kb>>3) + l4) * 128 + l15) * 8;
#pragma unroll
    for (int cf = 0; cf < 8; cf++){
      bf16x8 bb = *(const bf16x8*)(wp + bo + cf*128);
      MFMA16(acc[0][cf], a0, bb);
      MFMA16(acc[1][cf], a1, bb);
    }
  }

  if (w){
#pragma unroll
    for (int rf = 0; rf < 2; rf++)
#pragma unroll
      for (int cf = 0; cf < 8; cf++)
        red[w-1][(rf*8+cf)*64 + lane] = acc[rf][cf];
  }
  __syncthreads();
  if (!w){
#pragma unroll
    for (int rf = 0; rf < 2; rf++)
#pragma unroll
      for (int cf = 0; cf < 8; cf++){
        int i = (rf*8+cf)*64 + lane;
        f32x4 s = acc[rf][cf] + red[0][i] + red[1][i] + red[2][i];
        int col = cf*16 + l15;
#pragma unroll
        for (int r = 0; r < 4; r++){
          int hw = hw0 + rf*16 + l4*4 + r;
          if (hw < HW) G[gb + (size_t)hw*128 + col] = f2bf(s[r]);
        }
      }
  }
}

// ---------------------------------------------------------------- prep: gather-blend from G + vf base + x1/x2 pads + y1 tail-zero (both buffers)
__global__ void k_prep2(const float* __restrict__ vfeat, const float* __restrict__ pos,
                        const unsigned short* __restrict__ G,
                        const float* __restrict__ bias,
                        unsigned short* __restrict__ vf,
                        unsigned short* __restrict__ x1,
                        unsigned short* __restrict__ x2,
                        unsigned char* __restrict__ y1A,
                        unsigned char* __restrict__ y1B)
{
  int b = blockIdx.y;
  if (blockIdx.x == 0){
    unsigned long long* za = (unsigned long long*)(y1A + (size_t)b*YO + (size_t)328*128*8);
    unsigned long long* zb = (unsigned long long*)(y1B + (size_t)b*YO + (size_t)328*128*8);
    int i = threadIdx.x;
#pragma unroll
    for (int j = 0; j < 4; j++){ za[i*4+j] = 0; zb[i*4+j] = 0; }
  }
  int row = blockIdx.x * 4 + (threadIdx.x >> 6);
  int lane = threadIdx.x & 63;
  size_t vfo = ((size_t)b * MP + row) * 288;
  size_t xo  = ((size_t)b * MP + row) * 160;
  if (row < NVRT){
    size_t src = (size_t)b * NVRT + row;
    float px = fminf(fmaxf(pos[src*3 + 0], -1.f), 1.f);
    float py = fminf(fmaxf(pos[src*3 + 1], -1.f), 1.f);
    int c0 = lane * 2;
    float s0 = bias[c0], s1 = bias[c0 + 1];
#pragma unroll
    for (int m = 0; m < 4; m++){
      int W = 56 >> m;
      int HW = W * W;
      size_t gb = (m==0)?G_B0:(m==1)?G_B1:(m==2)?G_B2:G_B3;
      float gx = (px + 1.f) * 0.5f * (float)(W - 1);
      float gy = (py + 1.f) * 0.5f * (float)(W - 1);
      int x0 = (int)floorf(gx), y0 = (int)floorf(gy);
      float wx = gx - (float)x0, wy = gy - (float)y0;
      int x1i = min(x0 + 1, W - 1), y1i = min(y0 + 1, W - 1);
      const unsigned short* g = G + gb + (size_t)b * HW * 128;
      unsigned v00 = *(const unsigned*)(g + ((size_t)(y0 *W + x0 ))*128 + c0);
      unsigned v01 = *(const unsigned*)(g + ((size_t)(y0 *W + x1i))*128 + c0);
      unsigned v10 = *(const unsigned*)(g + ((size_t)(y1i*W + x0 ))*128 + c0);
      unsigned v11 = *(const unsigned*)(g + ((size_t)(y1i*W + x1i))*128 + c0);
      float w00 = (1.f-wx)*(1.f-wy), w01 = wx*(1.f-wy);
      float w10 = (1.f-wx)*wy,       w11 = wx*wy;
      s0 += w00*bflo(v00) + w01*bflo(v01) + w10*bflo(v10) + w11*bflo(v11);
      s1 += w00*bfhi(v00) + w01*bfhi(v01) + w10*bfhi(v10) + w11*bfhi(v11);
    }
    vf[vfo + 131 + c0]     = f2bf(s0);
    vf[vfo + 131 + c0 + 1] = f2bf(s1);
    float2 fv = *(const float2*)(vfeat + src*128 + c0);
    vf[vfo + c0]     = f2bf(fv.x);
    vf[vfo + c0 + 1] = f2bf(fv.y);
    if (lane < 3){
      unsigned short v = f2bf(pos[src*3 + lane]);
      vf[vfo + 128 + lane] = v;
      x1[xo + lane] = v;
      x2[xo + lane] = v;
    }
    if (lane >= 32 && lane < 61) vf[vfo + 259 + (lane - 32)] = 0;
    if (lane < 29){ x1[xo + 131 + lane] = 0; x2[xo + 131 + lane] = 0; }
  } else {
    for (int c = lane; c < 288; c += 64) vf[vfo + c] = 0;
    for (int c = lane; c < 160; c += 64){ x1[xo + c] = 0; x2[xo + c] = 0; }
  }
}

// ---------------------------------------------------------------- pack adjacency f32 -> fp8 e4m3 (x1024) MFMA tiles (HW cvt)
__global__ void k_adjpack8(const float* __restrict__ adj, unsigned char* __restrict__ adjP)
{
  int kt = blockIdx.x, rb = blockIdx.y, b = blockIdx.z;
  int t = threadIdx.x;
  int r = t >> 4, kseg = t & 15;
  int grow = rb*16 + r, gk = kt*128 + kseg*8;
  float v[8];
  if (grow < NVRT && gk + 8 <= NVRT){
    const float4* p = (const float4*)(adj + ((size_t)b*NVRT + grow)*NVRT + gk);
    float4 f0 = p[0], f1 = p[1];
    v[0]=f0.x; v[1]=f0.y; v[2]=f0.z; v[3]=f0.w;
    v[4]=f1.x; v[5]=f1.y; v[6]=f1.z; v[7]=f1.w;
  } else if (grow < NVRT){
    const float* ap = adj + ((size_t)b*NVRT + grow)*NVRT;
#pragma unroll
    for (int e = 0; e < 8; e++){ int k = gk + e; v[e] = (k < NVRT) ? ap[k] : 0.f; }
  } else {
#pragma unroll
    for (int e = 0; e < 8; e++) v[e] = 0.f;
  }
  unsigned lo = pk4_e4m3(v[0]*1024.f, v[1]*1024.f, v[2]*1024.f, v[3]*1024.f);
  unsigned hi = pk4_e4m3(v[4]*1024.f, v[5]*1024.f, v[6]*1024.f, v[7]*1024.f);
  unsigned long long q = (unsigned long long)lo | ((unsigned long long)hi << 32);
  unsigned char* tb = adjP + (((size_t)b*NRB16 + rb)*NKT8 + kt) * 2048;
  *(unsigned long long*)(tb + 128*r + 8*(kseg ^ r)) = q;
}

// ---------------------------------------------------------------- y1p8 = fp8(x @ w1)  (first gc only); batch-per-XCD grid
template<int KX>
__global__ __launch_bounds__(256) void k_y1(
    const unsigned short* __restrict__ x,
    const unsigned short* __restrict__ wp1,
    unsigned char* __restrict__ y1p8)
{
  int bid = blockIdx.x;
  int b = bid & 7, rb = (bid >> 3) * 32;
  int t = threadIdx.x, wave = t >> 6, lane = t & 63;
  int rf = wave & 1, ch = wave >> 1;
  int l15 = lane & 15, l4 = lane >> 4;
  f32x4 a1[4];
#pragma unroll
  for (int c = 0; c < 4; c++) a1[c] = (f32x4){0,0,0,0};
  int row = rb + rf*16 + l15;
  const unsigned short* xp = x + ((size_t)b * MP + row) * KX + l4 * 8;
#pragma unroll
  for (int kb = 0; kb < KX; kb += 32){
    bf16x8 a = *(const bf16x8*)(xp + kb);
    size_t bo = ((size_t)((kb>>3) + l4) * 128 + ch*64 + l15) * 8;
#pragma unroll
    for (int c = 0; c < 4; c++){
      bf16x8 b1 = *(const bf16x8*)(wp1 + bo + c*128);
      MFMA16(a1[c], a, b1);
    }
  }
  unsigned char* yb = y1p8 + (size_t)b * YO;
#pragma unroll
  for (int c = 0; c < 4; c++){
    int col = ch*64 + c*16 + l15;
    int orow0 = rb + rf*16 + l4*4;
    unsigned q = pk4_e4m3(a1[c][0], a1[c][1], a1[c][2], a1[c][3]);
    *(unsigned*)(yb + ((size_t)(orow0 >> 3) * 128 + col) * 8 + (orow0 & 7)) = q;
  }
}

// ---------------------------------------------------------------- h = relu(x@w0 + adj@y1/1024); LDS-staged fp8 adj GEMM + fused w0 GEMM
// batch-per-XCD grid (b = bid&7): each XCD's L2 keeps its batch's y1 panel hot
// EPI=0: writes xnext + fused NEXT-layer y1 (y1out, K=160); EPI=1: out_feat + lin1 head
template<int EPI, int KX>
__global__ __launch_bounds__(256) void k_adj8(
    const unsigned char* __restrict__ adjP,
    const unsigned char* __restrict__ y1in,
    const unsigned short* __restrict__ x,
    const unsigned short* __restrict__ wp0,
    const unsigned short* __restrict__ wp1n,
    unsigned char* __restrict__ y1out,
    const float* __restrict__ posg,
    unsigned short* __restrict__ xnext,
    float* __restrict__ outf,
    const float* __restrict__ wl1, const float* __restrict__ bl1,
    float* __restrict__ opos)
{
  __shared__ __align__(16) unsigned char abuf[2][2048];
  __shared__ unsigned short xbuf[EPI == 0 ? 16 : 1][168];
  __shared__ float hbuf[EPI == 1 ? 16 : 1][128];
  int bid = blockIdx.x;
  int b = bid & 7, rb = bid >> 3;
  int t = threadIdx.x, w = t >> 6, lane = t & 63;
  int l15 = lane & 15, l4 = lane >> 4;
  const unsigned char* tb = adjP + (((size_t)b*NRB16 + rb)*NKT8) * 2048;
  const unsigned char* yb = y1in + (size_t)b * YO;

  f32x4 acc[2], accW[2];
  acc[0] = (f32x4){0,0,0,0};  acc[1] = (f32x4){0,0,0,0};
  accW[0] = (f32x4){0,0,0,0}; accW[1] = (f32x4){0,0,0,0};

  auto stage = [&](int kt, int bufi){
    if (w < 2)
      gload_lds16(tb + (size_t)kt*2048 + w*1024 + lane*16, &abuf[bufi][w*1024]);
  };

  stage(0, 0);

  if (EPI == 0){
    if (t < 48){
      int r16 = t / 3, c = t - r16*3;
      int grow = rb*16 + r16;
      xbuf[r16][c] = (grow < NVRT) ? f2bf(posg[((size_t)b*NVRT + grow)*3 + c]) : 0;
    }
    {
      int r16 = t >> 4, c0 = 131 + (t & 15);
      xbuf[r16][c0] = 0;
      if (c0 + 16 < 168) xbuf[r16][c0 + 16] = 0;
      if (c0 + 32 < 168) xbuf[r16][c0 + 32] = 0;
    }
  }

  const unsigned short* xr = x + ((size_t)b*MP + rb*16 + l15)*KX + l4*8;
#pragma unroll
  for (int kb = 0; kb < KX; kb += 32){
    bf16x8 ax = *(const bf16x8*)(xr + kb);
    size_t bo = ((size_t)((kb>>3) + l4)*128 + w*32 + l15)*8;
    MFMA16(accW[0], ax, *(const bf16x8*)(wp0 + bo));
    MFMA16(accW[1], ax, *(const bf16x8*)(wp0 + bo + 128));
  }

  __syncthreads();

  for (int kt = 0; kt < NKT8; ++kt){
    int cur = kt & 1;
    if (kt < NKT8-1) stage(kt+1, cur ^ 1);
    const unsigned char* ab = &abuf[cur][0];
#pragma unroll
    for (int sel = 0; sel < 2; sel++){
#pragma unroll
      for (int ks = 0; ks < 2; ks++){
        int koct = sel*8 + ks*4 + l4;
        i64 a = *(const i64*)(ab + 128*l15 + 8*(koct ^ l15));
        const unsigned char* bp = yb + ((size_t)(kt*16 + koct)*128 + w*32 + l15)*8;
        i64 b0 = *(const i64*)(bp);
        i64 b1 = *(const i64*)(bp + 128);
        MFMA8(acc[0], a, b0);
        MFMA8(acc[1], a, b1);
      }
    }
    __syncthreads();
  }

#pragma unroll
  for (int cf = 0; cf < 2; cf++){
    int col = w*32 + cf*16 + l15;
#pragma unroll
    for (int r = 0; r < 4; r++){
      int row16 = l4*4 + r;
      int row = rb*16 + row16;
      float v = fmaxf(accW[cf][r] + acc[cf][r] * 0.0009765625f, 0.f);
      if (EPI == 0){
        unsigned short hb = f2bf(v);
        if (row < NVRT) xnext[((size_t)b*MP + row)*160 + 3 + col] = hb;
        xbuf[row16][3 + col] = hb;
      } else {
        if (row < NVRT) outf[((size_t)b*NVRT + row)*128 + col] = v;
        hbuf[row16][col] = v;
      }
    }
  }
  __syncthreads();

  if (EPI == 0){
    f32x4 accY[2];
    accY[0] = (f32x4){0,0,0,0}; accY[1] = (f32x4){0,0,0,0};
#pragma unroll
    for (int ks = 0; ks < 5; ks++){
      bf16x8 a = *(const bf16x8*)(&xbuf[l15][ks*32 + l4*8]);
      size_t bo = ((size_t)(ks*4 + l4)*128 + w*32 + l15)*8;
      MFMA16(accY[0], a, *(const bf16x8*)(wp1n + bo));
      MFMA16(accY[1], a, *(const bf16x8*)(wp1n + bo + 128));
    }
    unsigned char* yo = y1out + (size_t)b * YO;
#pragma unroll
    for (int cf = 0; cf < 2; cf++){
      int col = w*32 + cf*16 + l15;
      int orow0 = rb*16 + l4*4;
      unsigned q = pk4_e4m3(accY[cf][0], accY[cf][1], accY[cf][2], accY[cf][3]);
      *(unsigned*)(yo + ((size_t)(orow0 >> 3) * 128 + col) * 8 + (orow0 & 7)) = q;
    }
  } else {
#pragma unroll
    for (int rr = 0; rr < 4; rr++){
      int row16 = w*4 + rr;
      int grow = rb*16 + row16;
      if (grow < NVRT){
        int c0 = lane * 2;
        float v0 = hbuf[row16][c0], v1 = hbuf[row16][c0+1];
        float p[3];
#pragma unroll
        for (int j = 0; j < 3; j++){
          p[j] = v0 * wl1[c0*3 + j] + v1 * wl1[c0*3 + 3 + j];
#pragma unroll
          for (int off = 1; off < 64; off <<= 1)
            p[j] += __shfl_xor(p[j], off);
        }
        if (lane == 0){
          size_t po = ((size_t)b * NVRT + grow) * 3;
#pragma unroll
          for (int j = 0; j < 3; j++)
            opos[po + j] = posg[po + j] + tanhf(p[j] + bl1[j]);
        }
      }
    }
  }
}

// ================================================================ host
extern "C" void kernel_launch(void* const* d_in, const int* in_sizes, int n_in,
                              void* d_out, int out_size, void* d_ws, size_t ws_size,
                              hipStream_t stream)
{
  const float* conv[4] = {(const float*)d_in[0], (const float*)d_in[1],
                          (const float*)d_in[2], (const float*)d_in[3]};
  const float* adj   = (const float*)d_in[4];
  const float* pos   = (const float*)d_in[5];
  const float* vfeat = (const float*)d_in[6];
  const float* wlin0 = (const float*)d_in[7];
  const float* blin0 = (const float*)d_in[8];
  const float* gw[6] = {(const float*)d_in[9],  (const float*)d_in[10],
                        (const float*)d_in[11], (const float*)d_in[12],
                        (const float*)d_in[13], (const float*)d_in[14]};
  const float* wlin1 = (const float*)d_in[15];
  const float* blin1 = (const float*)d_in[16];

  char* ws = (char*)d_ws;
  size_t off = 0;
  auto take = [&](size_t bytes)->char* {
    char* p = ws + off;
    off += (bytes + 255) & ~(size_t)255;
    return p;
  };
  unsigned short* G    = (unsigned short*)take(G_TOT * 2);
  unsigned char*  adjP = (unsigned char*)take((size_t)NB*NRB16*NKT8*2048);
  unsigned short* wl0p = (unsigned short*)take((size_t)3840*128*2);
  unsigned short* w0p0 = (unsigned short*)take((size_t)288*128*2);
  unsigned short* w1p0 = (unsigned short*)take((size_t)288*128*2);
  unsigned short* w0p1 = (unsigned short*)take((size_t)160*128*2);
  unsigned short* w1p1 = (unsigned short*)take((size_t)160*128*2);
  unsigned short* w0p2 = (unsigned short*)take((size_t)160*128*2);
  unsigned short* w1p2 = (unsigned short*)take((size_t)160*128*2);
  unsigned short* vf   = (unsigned short*)take((size_t)NB*MP*288*2);
  unsigned short* x1   = (unsigned short*)take((size_t)NB*MP*160*2);
  unsigned short* x2   = (unsigned short*)take((size_t)NB*MP*160*2);
  unsigned char*  y1A  = (unsigned char*)take((size_t)NB*YO);
  unsigned char*  y1B  = (unsigned char*)take((size_t)NB*YO);

  float* out_pos  = (float*)d_out;
  float* out_feat = out_pos + (size_t)NB*NVRT*3;

  // 1. weight packing
  PWArgs pw;
  pw.src[0]=wlin0; pw.dst[0]=wl0p; pw.ksrc[0]=3840; pw.nsrc[0]=128;
  pw.src[1]=gw[0]; pw.dst[1]=w0p0; pw.ksrc[1]=259;  pw.nsrc[1]=131;
  pw.src[2]=gw[1]; pw.dst[2]=w1p0; pw.ksrc[2]=259;  pw.nsrc[2]=131;
  pw.src[3]=gw[2]; pw.dst[3]=w0p1; pw.ksrc[3]=131;  pw.nsrc[3]=128;
  pw.src[4]=gw[3]; pw.dst[4]=w1p1; pw.ksrc[4]=131;  pw.nsrc[4]=128;
  pw.src[5]=gw[4]; pw.dst[5]=w0p2; pw.ksrc[5]=131;  pw.nsrc[5]=128;
  pw.src[6]=gw[5]; pw.dst[6]=w1p2; pw.ksrc[6]=131;  pw.nsrc[6]=128;
  k_packw_all<<<2528, 256, 0, stream>>>(pw);
  // 2. fused conv transpose + pixel projection G = ft^T @ w_lin0
  k_gproj2<<<1056, 256, 0, stream>>>(conv[0], conv[1], conv[2], conv[3], wl0p, G);
  // 3. gather-blend + vf base + pads + y1 tail-zero (both buffers)
  k_prep2<<<dim3(MP/4, NB), 256, 0, stream>>>(vfeat, pos, G, blin0, vf, x1, x2, y1A, y1B);
  // 4. first y1 (from vf), batch-per-XCD
  k_y1<288><<<NRB2*NB, 256, 0, stream>>>(vf, w1p0, y1A);
  // 5. pack adjacency to fp8 swizzled tiles (x1024, HW convert)
  k_adjpack8<<<dim3(NKT8, NRB16, NB), 256, 0, stream>>>(adj, adjP);
  // 6-8. three graph convs, batch-per-XCD; each adj8<0> also emits the NEXT layer's y1
  k_adj8<0,288><<<NRB16*NB, 256, 0, stream>>>(adjP, y1A, vf, w0p0, w1p1, y1B, pos,
                                              x1, nullptr, nullptr, nullptr, nullptr);
  k_adj8<0,160><<<NRB16*NB, 256, 0, stream>>>(adjP, y1B, x1, w0p1, w1p2, y1A, pos,
                                              x2, nullptr, nullptr, nullptr, nullptr);
  k_adj8<1,160><<<NRB16*NB, 256, 0, stream>>>(adjP, y1A, x2, w0p2, nullptr, nullptr, pos,
                                              nullptr, out_feat, wlin1, blin1, out_pos);
  (void)in_sizes; (void)n_in; (void)out_size; (void)ws_size;
}